// Round 4
// baseline (2251.966 us; speedup 1.0000x reference)
//
#include <hip/hip_runtime.h>
#include <hip/hip_bf16.h>
#include <math.h>

// Problem constants: B,N,E,S,A,P,T
#define BG 512
#define NN 65536
#define EE 131072
#define SD 256
#define AD 512
#define PP 2
#define TD 64

typedef __attribute__((ext_vector_type(8))) short sx8;   // 8 bf16 (4 VGPRs)
typedef __attribute__((ext_vector_type(4))) short sx4;
typedef __attribute__((ext_vector_type(4))) float fx4;

__device__ __forceinline__ float bs2f(short s) {
    union { unsigned u; float f; } x; x.u = ((unsigned)(unsigned short)s) << 16; return x.f;
}
__device__ __forceinline__ short f2bs(float f) {
    union { float f; unsigned u; } x; x.f = f;
    unsigned r = x.u + 0x7fffu + ((x.u >> 16) & 1u);   // RNE (finite inputs)
    return (short)(r >> 16);
}
// branch-free fast tanh/sigmoid (v_exp_f32 path, clamped -> no inf/NaN)
__device__ __forceinline__ float fast_tanh(float x) {
    float xc = fminf(fmaxf(x, -15.f), 15.f);
    float e = __expf(2.f * xc);
    return __fdividef(e - 1.f, e + 1.f);
}
__device__ __forceinline__ float fast_sigm(float x) {
    float xc = fminf(fmaxf(x, -30.f), 30.f);
    float e = __expf(-xc);
    return __fdividef(1.f, 1.f + e);
}
__device__ __forceinline__ bool run_flag(const void* runv, int idx) {
    const unsigned char* r8 = (const unsigned char*)runv;
    const int* r32 = (const int*)runv;
    return (r8[idx] != 0) || (r32[idx] != 0);
}

// async global->LDS, 16B per lane; dest = wave-uniform base + lane*16
__device__ __forceinline__ void gload16(const short* g, short* l) {
    __builtin_amdgcn_global_load_lds(
        (const __attribute__((address_space(1))) void*)g,
        (__attribute__((address_space(3))) void*)l, 16, 0, 0);
}

// ---------------------------------------------------------------------------
// 128x128-tile bf16-MFMA GEMM:  C[m,n] = sum_k A[m,k] * W[n,k]  (+bias[n])
// A and W bf16, k-contiguous. global_load_lds staging, DOUBLE-BUFFERED:
// one barrier per K-step, next tile's loads issued before current compute.
// LDS XOR-swizzle on staging (both-sides: pre-swizzled global src + read XOR).
// 1-D grid, n-tile fastest + XCD-chunk swizzle (nwg%8==0 at all call sites).
// Epilogue (EPI 0/2): LDS-transpose the C tile (bf16 [128][128], chunk-XOR
// swizzled) -> vectorized sx8 gathers/stores instead of scalar 2B accesses.
//   EPI=0: store bf16 C (+bias)
//   EPI=2: store bf16 tanh(acc + nf[esrc[m]][cn] + nf[edst[m]][cn])  (fused T)
//   EPI=4: paired cols (16-row interleaved W): d=acc[ni]+bias[rc],
//          g=sigm(acc[ni+1]+bias2[rc]); store f32 d*g to Fout[m][rc]
// ---------------------------------------------------------------------------
template<int EPI>
__launch_bounds__(256, 4)
__global__ void gemm_bt(const short* __restrict__ Abp,
                        const short* __restrict__ Wp, const float* __restrict__ bias,
                        short* __restrict__ Cout, float* __restrict__ Fout,
                        const float* __restrict__ bias2,
                        const short* __restrict__ nfp,
                        const int* __restrict__ esrc, const int* __restrict__ edst,
                        int K, int NC, int NT)
{
    __shared__ __align__(16) short smem[16384];     // 32 KB: staging, then C-tile
    short* sA = smem;                               // 2 x 4096 shorts
    short* sB = smem + 8192;                        // 2 x 4096 shorts
    const int t = threadIdx.x;
    const int lane = t & 63;
    const int w = t >> 6;

    // XCD-chunk swizzle (m157): blocks sharing an A panel run on one XCD.
    const int nwg = gridDim.x;
    const int q = nwg >> 3;                     // nwg % 8 == 0 at every call site
    const int wg = (blockIdx.x & 7) * q + (blockIdx.x >> 3);
    const int mt = wg / NT;
    const int nt = wg - mt * NT;                // n fastest -> A-panel reuse in L2
    const int m0 = mt * 128;
    const int n0 = nt * 128;

    const int wm = (w >> 1) * 64;
    const int wn = (w & 1) * 64;
    const int lr = lane & 15;
    const int lg = lane >> 4;

    fx4 acc[4][4];
#pragma unroll
    for (int i = 0; i < 4; i++)
#pragma unroll
        for (int j = 0; j < 4; j++) { fx4 z = {0.f, 0.f, 0.f, 0.f}; acc[i][j] = z; }

    // staging: thread t covers row r=t>>2, 16B block cblk (XOR-swizzled source
    // so that physical LDS block (t&3) holds logical block (t&3)^((r>>1)&3)).
    // LDS dest stays linear: byte t*16 within each 64-row half (rule #21).
    const int r = t >> 2;
    const int cblk = (t & 3) ^ ((r >> 1) & 3);
    const short* gA = Abp + (size_t)(m0 + r) * K + cblk * 8;
    const short* gB = Wp + (size_t)(n0 + r) * K + cblk * 8;
    const size_t rowskip = (size_t)64 * K;      // (r+64)>>1 & 3 == r>>1 & 3

    auto STAGE = [&](int b, int kk) {
        gload16(gA + kk,           sA + b * 4096 + w * 512);
        gload16(gA + kk + rowskip, sA + b * 4096 + 2048 + w * 512);
        gload16(gB + kk,           sB + b * 4096 + w * 512);
        gload16(gB + kk + rowskip, sB + b * 4096 + 2048 + w * 512);
    };

    STAGE(0, 0);
    __syncthreads();                            // tile 0 ready
    int buf = 0;
    const int xa = (lr >> 1) & 3;               // read-side XOR row term
    for (int kk = 0; kk < K; kk += 32) {
        if (kk + 32 < K) STAGE(buf ^ 1, kk + 32);   // prefetch next tile
        const short* cA = sA + buf * 4096;
        const short* cB = sB + buf * 4096;
        sx8 af[4], bfr[4];
#pragma unroll
        for (int mi = 0; mi < 4; mi++)
            af[mi] = *(const sx8*)(cA + (wm + mi * 16 + lr) * 32 + (lg ^ xa) * 8);
#pragma unroll
        for (int ni = 0; ni < 4; ni++)
            bfr[ni] = *(const sx8*)(cB + (wn + ni * 16 + lr) * 32 + (lg ^ xa) * 8);
#pragma unroll
        for (int mi = 0; mi < 4; mi++)
#pragma unroll
            for (int ni = 0; ni < 4; ni++)
                acc[mi][ni] = __builtin_amdgcn_mfma_f32_16x16x32_bf16(
                    af[mi], bfr[ni], acc[mi][ni], 0, 0, 0);
        __syncthreads();                        // drains vmcnt (next tile) + lgkm
        buf ^= 1;
    }

    // D layout: col = lane&15, row = (lane>>4)*4 + reg
    if (EPI == 4) {
#pragma unroll
        for (int mi = 0; mi < 4; mi++) {
#pragma unroll
            for (int rg = 0; rg < 4; rg++) {
                const int m = m0 + wm + mi * 16 + lg * 4 + rg;
#pragma unroll
                for (int ni = 0; ni < 4; ni += 2) {
                    const int rc = (((n0 + wn + ni * 16) >> 5) << 4) + lr;
                    float dv = acc[mi][ni][rg] + bias[rc];
                    float gv = fast_sigm(acc[mi][ni + 1][rg] + bias2[rc]);
                    Fout[(size_t)m * 512 + rc] = dv * gv;
                }
            }
        }
    } else {
        // ---- LDS-transpose epilogue (EPI 0/2) ----
        // bf16 C tile [128][128], 16B-chunk XOR swizzle: phys_chunk = c ^ (row&15)
        short* sT = smem;
        const int rr = t >> 1;                  // read-phase row 0..127
        const int m = m0 + rr;
        int es = 0, ed = 0;
        if (EPI == 2) { es = esrc[m]; ed = edst[m]; }   // hoist before barrier
#pragma unroll
        for (int mi = 0; mi < 4; mi++) {
#pragma unroll
            for (int rg = 0; rg < 4; rg++) {
                const int rw = wm + mi * 16 + lg * 4 + rg;
                const int x = rw & 15;
#pragma unroll
                for (int ni = 0; ni < 4; ni++) {
                    const int col = wn + ni * 16 + lr;
                    float v = acc[mi][ni][rg];
                    if (bias) v += bias[n0 + col];
                    sT[rw * 128 + ((((col >> 3) ^ x) << 3) | (col & 7))] = f2bs(v);
                }
            }
        }
        __syncthreads();
        const int hbase = (t & 1) * 8;          // logical chunk half
        const short* ps = (EPI == 2) ? nfp + (size_t)es * NC + n0 : nullptr;
        const short* pd = (EPI == 2) ? nfp + (size_t)ed * NC + n0 : nullptr;
        short* co = Cout + (size_t)m * NC + n0;
        const int xr = rr & 15;
#pragma unroll
        for (int j = 0; j < 8; j++) {
            const int lc = hbase + j;           // logical chunk 0..15
            sx8 v = *(const sx8*)(sT + rr * 128 + ((lc ^ xr) << 3));
            if (EPI == 2) {
                sx8 a = *(const sx8*)(ps + lc * 8);
                sx8 b = *(const sx8*)(pd + lc * 8);
                sx8 o;
#pragma unroll
                for (int u = 0; u < 8; u++)
                    o[u] = f2bs(fast_tanh(bs2f(v[u]) + bs2f(a[u]) + bs2f(b[u])));
                *(sx8*)(co + lc * 8) = o;
            } else {
                *(sx8*)(co + lc * 8) = v;
            }
        }
    }
}

// f32 -> bf16 pre-cast (count divisible by 1024)
__global__ void k_castw(const float* __restrict__ in, short* __restrict__ out)
{
    size_t i = ((size_t)blockIdx.x * 256 + threadIdx.x) * 4;
    fx4 v = *(const fx4*)(in + i);
    sx4 o;
#pragma unroll
    for (int u = 0; u < 4; u++) o[u] = f2bs(v[u]);
    *(sx4*)(out + i) = o;
}

// stacked data/gate weights, 16-row interleave: out row r2 (of 1024):
// pair=r2>>5, kind=(r2>>4)&1, within=r2&15 -> src row pair*16+within of tW/gW
__global__ void k_cast_pair(const float* __restrict__ tW, const float* __restrict__ gW,
                            short* __restrict__ out)
{
    size_t i = ((size_t)blockIdx.x * 256 + threadIdx.x) * 4;   // 1024*256 elems
    const int r2 = (int)(i >> 8);
    const int c = (int)(i & 255);
    const int src = ((r2 >> 5) << 4) | (r2 & 15);
    const float* W = ((r2 >> 4) & 1) ? gW : tW;
    fx4 v = *(const fx4*)(W + (size_t)src * 256 + c);
    sx4 o;
#pragma unroll
    for (int u = 0; u < 4; u++) o[u] = f2bs(v[u]);
    *(sx4*)(out + i) = o;
}

// ---------------- CSR build ----------------
__global__ void k_count2(const int* __restrict__ a, const int* __restrict__ b,
                         int* __restrict__ deg, int n)
{
    int i = blockIdx.x * 256 + threadIdx.x;
    if (i < n) { atomicAdd(&deg[a[i]], 1); atomicAdd(&deg[b[i]], 1); }
}
__global__ void k_count1(const int* __restrict__ a, int* __restrict__ deg, int n)
{
    int i = blockIdx.x * 256 + threadIdx.x;
    if (i < n) atomicAdd(&deg[a[i]], 1);
}
// exclusive scan, single block of 256 threads, n divisible by 256
__global__ void k_scan(const int* __restrict__ deg, int* __restrict__ offs, int n)
{
    __shared__ int part[256];
    const int t = threadIdx.x;
    const int chunk = n >> 8;
    const int base = t * chunk;
    int s = 0;
    for (int i = 0; i < chunk; i++) s += deg[base + i];
    part[t] = s;
    __syncthreads();
    for (int off = 1; off < 256; off <<= 1) {
        int v = (t >= off) ? part[t - off] : 0;
        __syncthreads();
        part[t] += v;
        __syncthreads();
    }
    int run = (t > 0) ? part[t - 1] : 0;
    for (int i = 0; i < chunk; i++) {
        offs[base + i] = run;
        run += deg[base + i];
    }
    if (t == 255) offs[n] = part[255];
}
__global__ void k_fill2(const int* __restrict__ a, const int* __restrict__ b,
                        const int* __restrict__ offs, int* __restrict__ cur,
                        int* __restrict__ elist, int n)
{
    int i = blockIdx.x * 256 + threadIdx.x;
    if (i < n) {
        int p = atomicAdd(&cur[a[i]], 1); elist[offs[a[i]] + p] = i;
        int q = atomicAdd(&cur[b[i]], 1); elist[offs[b[i]] + q] = i;
    }
}
__global__ void k_fill1(const int* __restrict__ own, const int* __restrict__ offs,
                        int* __restrict__ cur, int* __restrict__ nlist, int n)
{
    int i = blockIdx.x * 256 + threadIdx.x;
    if (i < n) {
        int p = atomicAdd(&cur[own[i]], 1); nlist[offs[own[i]] + p] = i;
    }
}

// inputs[n,:] = sum over incident entries of msgs[e,:]  (bf16 in, bf16 out)
__global__ void k_edge_gather(const short* __restrict__ msgs, const int* __restrict__ offs,
                              const int* __restrict__ elist, short* __restrict__ inp)
{
    const int node = blockIdx.x * 4 + (threadIdx.x >> 6);  // 4 waves, 1 node each
    const int c = (threadIdx.x & 63) * 8;
    const int s0 = offs[node], s1 = offs[node + 1];
    float acc[8] = {0.f, 0.f, 0.f, 0.f, 0.f, 0.f, 0.f, 0.f};
    for (int s = s0; s < s1; s++) {
        const int e = elist[s];
        sx8 v = *(const sx8*)(msgs + (size_t)e * 512 + c);
#pragma unroll
        for (int u = 0; u < 8; u++) acc[u] += bs2f(v[u]);
    }
    sx8 o;
#pragma unroll
    for (int u = 0; u < 8; u++) o[u] = f2bs(acc[u]);
    *(sx8*)(inp + (size_t)node * 512 + c) = o;
}

// agg[b,:] = sum over nodes of owner b of gp[n,:]   (f32)
__global__ void k_owner_reduce(const float* __restrict__ gp, const int* __restrict__ offsB,
                               const int* __restrict__ nlist, float* __restrict__ agg)
{
    const int b = blockIdx.x, t = threadIdx.x;   // 256 threads, 2 cols each
    const int s0 = offsB[b], s1 = offsB[b + 1];
    float a0 = 0.f, a1 = 0.f;
    for (int s = s0; s < s1; s++) {
        const int n = nlist[s];
        float2 v = *(const float2*)(gp + (size_t)n * 512 + t * 2);
        a0 += v.x; a1 += v.y;
    }
    agg[(size_t)b * 512 + t * 2] = a0;
    agg[(size_t)b * 512 + t * 2 + 1] = a1;
}

// GRU combine: state kept bf16, updated in place. gates from gi/gh (bf16).
__global__ void k_gru(const short* __restrict__ gi, const short* __restrict__ gh,
                      short* __restrict__ nodes,
                      const int* __restrict__ owner, const void* __restrict__ runv)
{
    const int n = blockIdx.x * 4 + (threadIdx.x >> 6);   // 4 nodes/block
    const int t = threadIdx.x & 63;                      // 64 lanes, 4 cols each
    const bool run = run_flag(runv, owner[n]);
    const size_t gb = (size_t)n * 768 + t * 4;
    sx4 vir = *(const sx4*)(gi + gb);
    sx4 viz = *(const sx4*)(gi + gb + 256);
    sx4 vin = *(const sx4*)(gi + gb + 512);
    sx4 whr = *(const sx4*)(gh + gb);
    sx4 whz = *(const sx4*)(gh + gb + 256);
    sx4 whn = *(const sx4*)(gh + gb + 512);
    const size_t nbase = (size_t)n * 256 + t * 4;
    sx4 old4 = *(const sx4*)(nodes + nbase);
    sx4 outb;
#pragma unroll
    for (int u = 0; u < 4; u++) {
        float old = bs2f(old4[u]);
        float rr = fast_sigm(bs2f(vir[u]) + bs2f(whr[u]));
        float zz = fast_sigm(bs2f(viz[u]) + bs2f(whz[u]));
        float nn = fast_tanh(bs2f(vin[u]) + rr * bs2f(whn[u]));
        float nv = (1.f - zz) * nn + zz * old;
        outb[u] = run ? f2bs(nv) : old4[u];      // !run: bit-identical writeback
    }
    *(sx4*)(nodes + nbase) = outb;
}

// logits[b,:] = aggD[b,:] @ ntd_W.T + ntd_b   (f32)
__global__ void k_logits(const float* __restrict__ agg, const float* __restrict__ Wt,
                         const float* __restrict__ bt, float* __restrict__ logitsF,
                         float* __restrict__ outL)
{
    __shared__ float row[512];
    const int b = blockIdx.x, t = threadIdx.x;
    for (int k = t; k < 512; k += 128) row[k] = agg[(size_t)b * 512 + k];
    __syncthreads();
    if (t < TD + 1) {
        float acc = bt[t];
        const float* wr = Wt + (size_t)t * 512;
        for (int k = 0; k < 512; k++) acc += row[k] * wr[k];
        logitsF[b * (TD + 1) + t] = acc;
        outL[b * (TD + 1) + t] = acc;
    }
}

__global__ void k_loss(const float* __restrict__ logitsF, const int* __restrict__ reft,
                       const void* __restrict__ runv, float* __restrict__ outLoss)
{
    __shared__ float red[512];
    const int b = threadIdx.x;
    const float* lr = logitsF + b * (TD + 1);
    float mx = lr[0];
    for (int k = 1; k < TD + 1; k++) mx = fmaxf(mx, lr[k]);
    float se = 0.f;
    for (int k = 0; k < TD + 1; k++) se += expf(lr[k] - mx);
    const int sel = reft[b] + 1;
    float pe = logf(se) + mx - lr[sel];
    red[b] = run_flag(runv, b) ? pe : 0.f;
    __syncthreads();
    for (int s = 256; s > 0; s >>= 1) {
        if (b < s) red[b] += red[b + s];
        __syncthreads();
    }
    if (b == 0) outLoss[0] = red[0] / (float)BG;
}

__global__ void k_newfeat(const float* __restrict__ aggi, const float* __restrict__ nte,
                          const int* __restrict__ reft, const float* __restrict__ f1W,
                          const float* __restrict__ f1b, const float* __restrict__ f2W,
                          float* __restrict__ outNF)
{
    __shared__ float emb[256];
    __shared__ float ag[512];
    const int b = blockIdx.x, t = threadIdx.x;
    const int rt = reft[b];
    emb[t] = nte[(size_t)rt * 256 + t];
    ag[t] = aggi[(size_t)b * 512 + t];
    ag[t + 256] = aggi[(size_t)b * 512 + 256 + t];
    __syncthreads();
    float acc = f1b[t];
    const float* w1 = f1W + (size_t)t * 256;
    for (int k = 0; k < 256; k++) acc += emb[k] * w1[k];
    const float* w2 = f2W + (size_t)t * 512;
    for (int a = 0; a < 512; a++) acc += ag[a] * w2[a];
    outNF[(size_t)b * 256 + t] = acc;
}

extern "C" void kernel_launch(void* const* d_in, const int* in_sizes, int n_in,
                              void* d_out, int out_size, void* d_ws, size_t ws_size,
                              hipStream_t stream)
{
    (void)in_sizes; (void)n_in; (void)out_size;
    const float* in_nodes = (const float*)d_in[0];
    const float* in_ef    = (const float*)d_in[1];
    const int*   e_src    = (const int*)d_in[2];
    const int*   e_dst    = (const int*)d_in[3];
    const int*   owner    = (const int*)d_in[4];
    const void*  running  = d_in[5];
    const int*   reft     = (const int*)d_in[6];
    const float* dec_tW = (const float*)d_in[7];
    const float* dec_tb = (const float*)d_in[8];
    const float* dec_gW = (const float*)d_in[9];
    const float* dec_gb = (const float*)d_in[10];
    const float* init_tW = (const float*)d_in[11];
    const float* init_tb = (const float*)d_in[12];
    const float* init_gW = (const float*)d_in[13];
    const float* init_gb = (const float*)d_in[14];
    const float* ntdW = (const float*)d_in[15];
    const float* ntdb = (const float*)d_in[16];
    const float* nte  = (const float*)d_in[17];
    const float* f1W  = (const float*)d_in[18];
    const float* f1b  = (const float*)d_in[19];
    const float* f2W  = (const float*)d_in[20];
    const float* mnW  = (const float*)d_in[21];
    const float* mfW  = (const float*)d_in[22];
    const float* ml2W = (const float*)d_in[23];
    const float* ml2b = (const float*)d_in[24];
    const float* Wih  = (const float*)d_in[25];
    const float* Whh  = (const float*)d_in[26];
    const float* bih  = (const float*)d_in[27];
    const float* bhh  = (const float*)d_in[28];

    float* outL    = (float*)d_out;                        // [512,65] f32
    float* outNF   = outL + BG * (TD + 1);                 // [512,256] f32
    float* outLoss = outNF + BG * SD;                      // [1] f32

    size_t off = 0;
    auto take = [&](size_t bytes) -> void* {
        void* p = (char*)d_ws + off;
        off += (bytes + 255) & ~(size_t)255;
        return p;
    };
    short* nodes_bf  = (short*)take((size_t)NN * SD * 2);      // 33 MB bf16 state
    short* ef_bf     = (short*)take((size_t)EE * SD * 2);      // 67 MB bf16 edge feats
    short* bufC      = (short*)take((size_t)NN * 512 * 2);     // nf
    short* bufD      = (short*)take((size_t)EE * 512 * 2);     // T, later gi[N,768]
    short* bufM      = (short*)take((size_t)EE * 512 * 2);     // msgs, later gh / gp(f32)
    short* bufI      = (short*)take((size_t)NN * 512 * 2);     // inputs bf16
    float* aggD      = (float*)take((size_t)BG * AD * 4);
    float* aggI      = (float*)take((size_t)BG * AD * 4);
    float* logitsF   = (float*)take((size_t)BG * (TD + 1) * 4);
    // bf16 weight copies
    short* mnWb  = (short*)take((size_t)PP * 512 * 256 * 2);
    short* mfWb  = (short*)take((size_t)PP * 512 * 256 * 2);
    short* ml2Wb = (short*)take((size_t)PP * 512 * 512 * 2);
    short* WihB  = (short*)take((size_t)PP * 768 * 512 * 2);
    short* WhhB  = (short*)take((size_t)PP * 768 * 256 * 2);
    short* W2dec = (short*)take((size_t)1024 * 256 * 2);       // interleaved dt/dg
    short* W2ini = (short*)take((size_t)1024 * 256 * 2);       // interleaved it/ig
    // CSR buffers
    int* deg_e = (int*)take((size_t)NN * 4);
    int* offs_e = (int*)take((size_t)(NN + 1) * 4);
    int* cur_e = (int*)take((size_t)NN * 4);
    int* elist = (int*)take((size_t)2 * EE * 4);
    int* degB = (int*)take((size_t)BG * 4);
    int* offsB = (int*)take((size_t)(BG + 1) * 4);
    int* curB = (int*)take((size_t)BG * 4);
    int* nlist = (int*)take((size_t)NN * 4);
    if (off > ws_size) return;

    short* gi = bufD;            // [N,768] bf16 (T dead by then)
    short* gh = bufM;            // [N,768] bf16 (msgs dead by then)
    float* gp = (float*)bufM;    // [N,512] f32 (gh dead by then) — 134 MB fits exactly

    // activation pre-casts (enables global_load_lds path everywhere)
    k_castw<<<NN * SD / 1024, 256, 0, stream>>>(in_nodes, nodes_bf);
    k_castw<<<EE * SD / 1024, 256, 0, stream>>>(in_ef, ef_bf);
    // weight pre-casts
    k_castw<<<PP * 512 * 256 / 1024, 256, 0, stream>>>(mnW, mnWb);
    k_castw<<<PP * 512 * 256 / 1024, 256, 0, stream>>>(mfW, mfWb);
    k_castw<<<PP * 512 * 512 / 1024, 256, 0, stream>>>(ml2W, ml2Wb);
    k_castw<<<PP * 768 * 512 / 1024, 256, 0, stream>>>(Wih, WihB);
    k_castw<<<PP * 768 * 256 / 1024, 256, 0, stream>>>(Whh, WhhB);
    k_cast_pair<<<1024 * 256 / 1024, 256, 0, stream>>>(dec_tW, dec_gW, W2dec);
    k_cast_pair<<<1024 * 256 / 1024, 256, 0, stream>>>(init_tW, init_gW, W2ini);

    // CSR builds (once per launch)
    hipMemsetAsync(deg_e, 0, (size_t)NN * 4, stream);
    hipMemsetAsync(cur_e, 0, (size_t)NN * 4, stream);
    hipMemsetAsync(degB, 0, (size_t)BG * 4, stream);
    hipMemsetAsync(curB, 0, (size_t)BG * 4, stream);
    k_count2<<<(EE + 255) / 256, 256, 0, stream>>>(e_src, e_dst, deg_e, EE);
    k_scan<<<1, 256, 0, stream>>>(deg_e, offs_e, NN);
    k_fill2<<<(EE + 255) / 256, 256, 0, stream>>>(e_src, e_dst, offs_e, cur_e, elist, EE);
    k_count1<<<(NN + 255) / 256, 256, 0, stream>>>(owner, degB, NN);
    k_scan<<<1, 256, 0, stream>>>(degB, offsB, BG);
    k_fill1<<<(NN + 255) / 256, 256, 0, stream>>>(owner, offsB, curB, nlist, NN);

    for (int p = 0; p < PP; p++) {
        // nf = nodes @ mn_W.T            [N,512] bf16
        gemm_bt<0><<<NN / 128 * 4, 256, 0, stream>>>(
            nodes_bf, mnWb + (size_t)p * 512 * 256, nullptr, bufC,
            nullptr, nullptr, nullptr, nullptr, nullptr, 256, 512, 4);
        // T = tanh(nf[src]+nf[dst] + ef@mf_W.T)   [E,512] bf16 (fused epilogue)
        gemm_bt<2><<<EE / 128 * 4, 256, 0, stream>>>(
            ef_bf, mfWb + (size_t)p * 512 * 256, nullptr, bufD,
            nullptr, nullptr, bufC, e_src, e_dst, 256, 512, 4);
        // msgs = T @ ml2.T + ml2_b       [E,512] bf16
        gemm_bt<0><<<EE / 128 * 4, 256, 0, stream>>>(
            bufD, ml2Wb + (size_t)p * 512 * 512, ml2b + (size_t)p * 512,
            bufM, nullptr, nullptr, nullptr, nullptr, nullptr, 512, 512, 4);
        // inputs[n] = sum of msgs over incident edges (CSR gather)
        k_edge_gather<<<NN / 4, 256, 0, stream>>>(bufM, offs_e, elist, bufI);
        // gi = inputs @ Wih.T + bih      [N,768] bf16 (into bufD; T dead)
        gemm_bt<0><<<NN / 128 * 6, 256, 0, stream>>>(
            bufI, WihB + (size_t)p * 768 * 512, bih + (size_t)p * 768, gi,
            nullptr, nullptr, nullptr, nullptr, nullptr, 512, 768, 6);
        // gh = nodes @ Whh.T + bhh       [N,768] bf16 (into bufM; msgs dead)
        gemm_bt<0><<<NN / 128 * 6, 256, 0, stream>>>(
            nodes_bf, WhhB + (size_t)p * 768 * 256, bhh + (size_t)p * 768, gh,
            nullptr, nullptr, nullptr, nullptr, nullptr, 256, 768, 6);
        // GRU combine -> nodes_bf (in place, bf16 state)
        k_gru<<<NN / 4, 256, 0, stream>>>(gi, gh, nodes_bf, owner, running);
    }

    // decision aggregator: single fused GEMM (interleaved data/gate W, NC=1024)
    gemm_bt<4><<<NN / 128 * 8, 256, 0, stream>>>(
        nodes_bf, W2dec, dec_tb, nullptr, gp, dec_gb,
        nullptr, nullptr, nullptr, 256, 1024, 8);
    k_owner_reduce<<<BG, 256, 0, stream>>>(gp, offsB, nlist, aggD);
    // init aggregator
    gemm_bt<4><<<NN / 128 * 8, 256, 0, stream>>>(
        nodes_bf, W2ini, init_tb, nullptr, gp, init_gb,
        nullptr, nullptr, nullptr, 256, 1024, 8);
    k_owner_reduce<<<BG, 256, 0, stream>>>(gp, offsB, nlist, aggI);

    k_logits<<<BG, 128, 0, stream>>>(aggD, ntdW, ntdb, logitsF, outL);
    k_loss<<<1, 512, 0, stream>>>(logitsF, reft, running, outLoss);
    k_newfeat<<<BG, 256, 0, stream>>>(aggI, nte, reft, f1W, f1b, f2W, outNF);
}

// Round 5
// 1886.021 us; speedup vs baseline: 1.1940x; 1.1940x over previous
//
#include <hip/hip_runtime.h>
#include <hip/hip_bf16.h>
#include <math.h>

// Problem constants: B,N,E,S,A,P,T
#define BG 512
#define NN 65536
#define EE 131072
#define SD 256
#define AD 512
#define PP 2
#define TD 64

typedef __attribute__((ext_vector_type(8))) short sx8;   // 8 bf16 (4 VGPRs)
typedef __attribute__((ext_vector_type(4))) short sx4;
typedef __attribute__((ext_vector_type(4))) float fx4;

__device__ __forceinline__ float bs2f(short s) {
    union { unsigned u; float f; } x; x.u = ((unsigned)(unsigned short)s) << 16; return x.f;
}
__device__ __forceinline__ short f2bs(float f) {
    union { float f; unsigned u; } x; x.f = f;
    unsigned r = x.u + 0x7fffu + ((x.u >> 16) & 1u);   // RNE (finite inputs)
    return (short)(r >> 16);
}
// branch-free fast tanh/sigmoid (v_exp_f32 path, clamped -> no inf/NaN)
__device__ __forceinline__ float fast_tanh(float x) {
    float xc = fminf(fmaxf(x, -15.f), 15.f);
    float e = __expf(2.f * xc);
    return __fdividef(e - 1.f, e + 1.f);
}
__device__ __forceinline__ float fast_sigm(float x) {
    float xc = fminf(fmaxf(x, -30.f), 30.f);
    float e = __expf(-xc);
    return __fdividef(1.f, 1.f + e);
}
__device__ __forceinline__ bool run_flag(const void* runv, int idx) {
    const unsigned char* r8 = (const unsigned char*)runv;
    const int* r32 = (const int*)runv;
    return (r8[idx] != 0) || (r32[idx] != 0);
}

// async global->LDS, 16B per lane; dest = wave-uniform base + lane*16
__device__ __forceinline__ void gload16(const short* g, short* l) {
    __builtin_amdgcn_global_load_lds(
        (const __attribute__((address_space(1))) void*)g,
        (__attribute__((address_space(3))) void*)l, 16, 0, 0);
}

// ---------------------------------------------------------------------------
// 128x128-tile bf16-MFMA GEMM:  C[m,n] = sum_k A[m,k] * W[n,k]  (+bias[n])
// A and W bf16, k-contiguous. global_load_lds staging, DOUBLE-BUFFERED:
// one barrier per K-step, next tile's loads issued before current compute.
// LDS XOR-swizzle on staging (both-sides: pre-swizzled global src + read XOR).
// 1-D grid, n-tile fastest + XCD-chunk swizzle (nwg%8==0 at all call sites).
// EPI 0/2 use SWAPPED mfma operands: mfma(W_frag, A_frag) -> C^T fragment
// layout where lane&15 = row m (edge) and regs hold 4 CONSECUTIVE columns.
// Epilogue then does 8B vector gathers/stores (per-instruction coalesced,
// 16 rows x 32B contiguous) instead of 2B scalars.  [round-4 LDS-transpose
// reverted: 16B-scattered stores caused 2x HBM write amplification]
//   EPI=0: store bf16 C (+bias)
//   EPI=2: store bf16 tanh(acc + nf[esrc[m]][cn] + nf[edst[m]][cn])  (fused T)
//   EPI=4: (unswapped) paired cols, 16-row interleaved W: d=acc[ni]+bias[rc],
//          g=sigm(acc[ni+1]+bias2[rc]); store f32 d*g to Fout[m][rc]
// ---------------------------------------------------------------------------
template<int EPI>
__launch_bounds__(256, 4)
__global__ void gemm_bt(const short* __restrict__ Abp,
                        const short* __restrict__ Wp, const float* __restrict__ bias,
                        short* __restrict__ Cout, float* __restrict__ Fout,
                        const float* __restrict__ bias2,
                        const short* __restrict__ nfp,
                        const int* __restrict__ esrc, const int* __restrict__ edst,
                        int K, int NC, int NT)
{
    __shared__ __align__(16) short sA[2 * 4096];
    __shared__ __align__(16) short sB[2 * 4096];
    const int t = threadIdx.x;
    const int lane = t & 63;
    const int w = t >> 6;

    // XCD-chunk swizzle (m157): blocks sharing an A panel run on one XCD.
    const int nwg = gridDim.x;
    const int q = nwg >> 3;                     // nwg % 8 == 0 at every call site
    const int wg = (blockIdx.x & 7) * q + (blockIdx.x >> 3);
    const int mt = wg / NT;
    const int nt = wg - mt * NT;                // n fastest -> A-panel reuse in L2
    const int m0 = mt * 128;
    const int n0 = nt * 128;

    const int wm = (w >> 1) * 64;
    const int wn = (w & 1) * 64;
    const int lr = lane & 15;
    const int lg = lane >> 4;

    fx4 acc[4][4];
#pragma unroll
    for (int i = 0; i < 4; i++)
#pragma unroll
        for (int j = 0; j < 4; j++) { fx4 z = {0.f, 0.f, 0.f, 0.f}; acc[i][j] = z; }

    // staging: thread t covers row r=t>>2, 16B block cblk (XOR-swizzled source
    // so that physical LDS block (t&3) holds logical block (t&3)^((r>>1)&3)).
    // LDS dest stays linear: byte t*16 within each 64-row half (rule #21).
    const int r = t >> 2;
    const int cblk = (t & 3) ^ ((r >> 1) & 3);
    const short* gA = Abp + (size_t)(m0 + r) * K + cblk * 8;
    const short* gB = Wp + (size_t)(n0 + r) * K + cblk * 8;
    const size_t rowskip = (size_t)64 * K;      // (r+64)>>1 & 3 == r>>1 & 3

    auto STAGE = [&](int b, int kk) {
        gload16(gA + kk,           sA + b * 4096 + w * 512);
        gload16(gA + kk + rowskip, sA + b * 4096 + 2048 + w * 512);
        gload16(gB + kk,           sB + b * 4096 + w * 512);
        gload16(gB + kk + rowskip, sB + b * 4096 + 2048 + w * 512);
    };

    STAGE(0, 0);
    __syncthreads();                            // tile 0 ready
    int buf = 0;
    const int xa = (lr >> 1) & 3;               // read-side XOR row term
    for (int kk = 0; kk < K; kk += 32) {
        if (kk + 32 < K) STAGE(buf ^ 1, kk + 32);   // prefetch next tile
        const short* cA = sA + buf * 4096;
        const short* cB = sB + buf * 4096;
        sx8 af[4], bfr[4];
#pragma unroll
        for (int mi = 0; mi < 4; mi++)
            af[mi] = *(const sx8*)(cA + (wm + mi * 16 + lr) * 32 + (lg ^ xa) * 8);
#pragma unroll
        for (int ni = 0; ni < 4; ni++)
            bfr[ni] = *(const sx8*)(cB + (wn + ni * 16 + lr) * 32 + (lg ^ xa) * 8);
#pragma unroll
        for (int mi = 0; mi < 4; mi++)
#pragma unroll
            for (int ni = 0; ni < 4; ni++) {
                if (EPI == 4)       // normal: col=lane&15 -> n
                    acc[mi][ni] = __builtin_amdgcn_mfma_f32_16x16x32_bf16(
                        af[mi], bfr[ni], acc[mi][ni], 0, 0, 0);
                else                // swapped: col=lane&15 -> m, regs -> 4 consec n
                    acc[mi][ni] = __builtin_amdgcn_mfma_f32_16x16x32_bf16(
                        bfr[ni], af[mi], acc[mi][ni], 0, 0, 0);
            }
        __syncthreads();                        // drains vmcnt (next tile) + lgkm
        buf ^= 1;
    }

    if (EPI == 4) {
        // D layout: col = lane&15 (n within 16), row = (lane>>4)*4 + reg (m)
#pragma unroll
        for (int mi = 0; mi < 4; mi++) {
#pragma unroll
            for (int rg = 0; rg < 4; rg++) {
                const int m = m0 + wm + mi * 16 + lg * 4 + rg;
#pragma unroll
                for (int ni = 0; ni < 4; ni += 2) {
                    const int rc = (((n0 + wn + ni * 16) >> 5) << 4) + lr;
                    float dv = acc[mi][ni][rg] + bias[rc];
                    float gv = fast_sigm(acc[mi][ni + 1][rg] + bias2[rc]);
                    Fout[(size_t)m * 512 + rc] = dv * gv;
                }
            }
        }
    } else {
        // swapped D layout: m = m0+wm+mi*16+(lane&15); n = n0+wn+ni*16+lg*4+rg
#pragma unroll
        for (int mi = 0; mi < 4; mi++) {
            const int m = m0 + wm + mi * 16 + lr;
            if (EPI == 2) {
                const int es = esrc[m], ed = edst[m];
                const short* ps = nfp + (size_t)es * NC + n0;
                const short* pd = nfp + (size_t)ed * NC + n0;
                short* co = Cout + (size_t)m * NC + n0;
#pragma unroll
                for (int ni = 0; ni < 4; ni++) {
                    const int nc = wn + ni * 16 + lg * 4;
                    sx4 a4 = *(const sx4*)(ps + nc);
                    sx4 b4 = *(const sx4*)(pd + nc);
                    sx4 o;
#pragma unroll
                    for (int rg = 0; rg < 4; rg++)
                        o[rg] = f2bs(fast_tanh(acc[mi][ni][rg]
                                               + bs2f(a4[rg]) + bs2f(b4[rg])));
                    *(sx4*)(co + nc) = o;
                }
            } else {                            // EPI == 0
                short* co = Cout + (size_t)m * NC + n0;
#pragma unroll
                for (int ni = 0; ni < 4; ni++) {
                    const int nc = wn + ni * 16 + lg * 4;
                    fx4 vb = {0.f, 0.f, 0.f, 0.f};
                    if (bias) vb = *(const fx4*)(bias + n0 + nc);
                    sx4 o;
#pragma unroll
                    for (int rg = 0; rg < 4; rg++)
                        o[rg] = f2bs(acc[mi][ni][rg] + vb[rg]);
                    *(sx4*)(co + nc) = o;
                }
            }
        }
    }
}

// f32 -> bf16 pre-cast (count divisible by 1024)
__global__ void k_castw(const float* __restrict__ in, short* __restrict__ out)
{
    size_t i = ((size_t)blockIdx.x * 256 + threadIdx.x) * 4;
    fx4 v = *(const fx4*)(in + i);
    sx4 o;
#pragma unroll
    for (int u = 0; u < 4; u++) o[u] = f2bs(v[u]);
    *(sx4*)(out + i) = o;
}

// stacked data/gate weights, 16-row interleave: out row r2 (of 1024):
// pair=r2>>5, kind=(r2>>4)&1, within=r2&15 -> src row pair*16+within of tW/gW
__global__ void k_cast_pair(const float* __restrict__ tW, const float* __restrict__ gW,
                            short* __restrict__ out)
{
    size_t i = ((size_t)blockIdx.x * 256 + threadIdx.x) * 4;   // 1024*256 elems
    const int r2 = (int)(i >> 8);
    const int c = (int)(i & 255);
    const int src = ((r2 >> 5) << 4) | (r2 & 15);
    const float* W = ((r2 >> 4) & 1) ? gW : tW;
    fx4 v = *(const fx4*)(W + (size_t)src * 256 + c);
    sx4 o;
#pragma unroll
    for (int u = 0; u < 4; u++) o[u] = f2bs(v[u]);
    *(sx4*)(out + i) = o;
}

// ---------------- CSR build ----------------
__global__ void k_count2(const int* __restrict__ a, const int* __restrict__ b,
                         int* __restrict__ deg, int n)
{
    int i = blockIdx.x * 256 + threadIdx.x;
    if (i < n) { atomicAdd(&deg[a[i]], 1); atomicAdd(&deg[b[i]], 1); }
}
__global__ void k_count1(const int* __restrict__ a, int* __restrict__ deg, int n)
{
    int i = blockIdx.x * 256 + threadIdx.x;
    if (i < n) atomicAdd(&deg[a[i]], 1);
}
// exclusive scan, single block of 256 threads, n divisible by 256
__global__ void k_scan(const int* __restrict__ deg, int* __restrict__ offs, int n)
{
    __shared__ int part[256];
    const int t = threadIdx.x;
    const int chunk = n >> 8;
    const int base = t * chunk;
    int s = 0;
    for (int i = 0; i < chunk; i++) s += deg[base + i];
    part[t] = s;
    __syncthreads();
    for (int off = 1; off < 256; off <<= 1) {
        int v = (t >= off) ? part[t - off] : 0;
        __syncthreads();
        part[t] += v;
        __syncthreads();
    }
    int run = (t > 0) ? part[t - 1] : 0;
    for (int i = 0; i < chunk; i++) {
        offs[base + i] = run;
        run += deg[base + i];
    }
    if (t == 255) offs[n] = part[255];
}
__global__ void k_fill2(const int* __restrict__ a, const int* __restrict__ b,
                        const int* __restrict__ offs, int* __restrict__ cur,
                        int* __restrict__ elist, int n)
{
    int i = blockIdx.x * 256 + threadIdx.x;
    if (i < n) {
        int p = atomicAdd(&cur[a[i]], 1); elist[offs[a[i]] + p] = i;
        int q = atomicAdd(&cur[b[i]], 1); elist[offs[b[i]] + q] = i;
    }
}
__global__ void k_fill1(const int* __restrict__ own, const int* __restrict__ offs,
                        int* __restrict__ cur, int* __restrict__ nlist, int n)
{
    int i = blockIdx.x * 256 + threadIdx.x;
    if (i < n) {
        int p = atomicAdd(&cur[own[i]], 1); nlist[offs[own[i]] + p] = i;
    }
}

// inputs[n,:] = sum over incident entries of msgs[e,:]  (bf16 in, bf16 out)
__global__ void k_edge_gather(const short* __restrict__ msgs, const int* __restrict__ offs,
                              const int* __restrict__ elist, short* __restrict__ inp)
{
    const int node = blockIdx.x * 4 + (threadIdx.x >> 6);  // 4 waves, 1 node each
    const int c = (threadIdx.x & 63) * 8;
    const int s0 = offs[node], s1 = offs[node + 1];
    float acc[8] = {0.f, 0.f, 0.f, 0.f, 0.f, 0.f, 0.f, 0.f};
    for (int s = s0; s < s1; s++) {
        const int e = elist[s];
        sx8 v = *(const sx8*)(msgs + (size_t)e * 512 + c);
#pragma unroll
        for (int u = 0; u < 8; u++) acc[u] += bs2f(v[u]);
    }
    sx8 o;
#pragma unroll
    for (int u = 0; u < 8; u++) o[u] = f2bs(acc[u]);
    *(sx8*)(inp + (size_t)node * 512 + c) = o;
}

// agg[b,:] = sum over nodes of owner b of gp[n,:]   (f32)
__global__ void k_owner_reduce(const float* __restrict__ gp, const int* __restrict__ offsB,
                               const int* __restrict__ nlist, float* __restrict__ agg)
{
    const int b = blockIdx.x, t = threadIdx.x;   // 256 threads, 2 cols each
    const int s0 = offsB[b], s1 = offsB[b + 1];
    float a0 = 0.f, a1 = 0.f;
    for (int s = s0; s < s1; s++) {
        const int n = nlist[s];
        float2 v = *(const float2*)(gp + (size_t)n * 512 + t * 2);
        a0 += v.x; a1 += v.y;
    }
    agg[(size_t)b * 512 + t * 2] = a0;
    agg[(size_t)b * 512 + t * 2 + 1] = a1;
}

// GRU combine: state kept bf16, updated in place. gates from gi/gh (bf16).
__global__ void k_gru(const short* __restrict__ gi, const short* __restrict__ gh,
                      short* __restrict__ nodes,
                      const int* __restrict__ owner, const void* __restrict__ runv)
{
    const int n = blockIdx.x * 4 + (threadIdx.x >> 6);   // 4 nodes/block
    const int t = threadIdx.x & 63;                      // 64 lanes, 4 cols each
    const bool run = run_flag(runv, owner[n]);
    const size_t gb = (size_t)n * 768 + t * 4;
    sx4 vir = *(const sx4*)(gi + gb);
    sx4 viz = *(const sx4*)(gi + gb + 256);
    sx4 vin = *(const sx4*)(gi + gb + 512);
    sx4 whr = *(const sx4*)(gh + gb);
    sx4 whz = *(const sx4*)(gh + gb + 256);
    sx4 whn = *(const sx4*)(gh + gb + 512);
    const size_t nbase = (size_t)n * 256 + t * 4;
    sx4 old4 = *(const sx4*)(nodes + nbase);
    sx4 outb;
#pragma unroll
    for (int u = 0; u < 4; u++) {
        float old = bs2f(old4[u]);
        float rr = fast_sigm(bs2f(vir[u]) + bs2f(whr[u]));
        float zz = fast_sigm(bs2f(viz[u]) + bs2f(whz[u]));
        float nn = fast_tanh(bs2f(vin[u]) + rr * bs2f(whn[u]));
        float nv = (1.f - zz) * nn + zz * old;
        outb[u] = run ? f2bs(nv) : old4[u];      // !run: bit-identical writeback
    }
    *(sx4*)(nodes + nbase) = outb;
}

// logits[b,:] = aggD[b,:] @ ntd_W.T + ntd_b   (f32)
__global__ void k_logits(const float* __restrict__ agg, const float* __restrict__ Wt,
                         const float* __restrict__ bt, float* __restrict__ logitsF,
                         float* __restrict__ outL)
{
    __shared__ float row[512];
    const int b = blockIdx.x, t = threadIdx.x;
    for (int k = t; k < 512; k += 128) row[k] = agg[(size_t)b * 512 + k];
    __syncthreads();
    if (t < TD + 1) {
        float acc = bt[t];
        const float* wr = Wt + (size_t)t * 512;
        for (int k = 0; k < 512; k++) acc += row[k] * wr[k];
        logitsF[b * (TD + 1) + t] = acc;
        outL[b * (TD + 1) + t] = acc;
    }
}

__global__ void k_loss(const float* __restrict__ logitsF, const int* __restrict__ reft,
                       const void* __restrict__ runv, float* __restrict__ outLoss)
{
    __shared__ float red[512];
    const int b = threadIdx.x;
    const float* lr = logitsF + b * (TD + 1);
    float mx = lr[0];
    for (int k = 1; k < TD + 1; k++) mx = fmaxf(mx, lr[k]);
    float se = 0.f;
    for (int k = 0; k < TD + 1; k++) se += expf(lr[k] - mx);
    const int sel = reft[b] + 1;
    float pe = logf(se) + mx - lr[sel];
    red[b] = run_flag(runv, b) ? pe : 0.f;
    __syncthreads();
    for (int s = 256; s > 0; s >>= 1) {
        if (b < s) red[b] += red[b + s];
        __syncthreads();
    }
    if (b == 0) outLoss[0] = red[0] / (float)BG;
}

__global__ void k_newfeat(const float* __restrict__ aggi, const float* __restrict__ nte,
                          const int* __restrict__ reft, const float* __restrict__ f1W,
                          const float* __restrict__ f1b, const float* __restrict__ f2W,
                          float* __restrict__ outNF)
{
    __shared__ float emb[256];
    __shared__ float ag[512];
    const int b = blockIdx.x, t = threadIdx.x;
    const int rt = reft[b];
    emb[t] = nte[(size_t)rt * 256 + t];
    ag[t] = aggi[(size_t)b * 512 + t];
    ag[t + 256] = aggi[(size_t)b * 512 + 256 + t];
    __syncthreads();
    float acc = f1b[t];
    const float* w1 = f1W + (size_t)t * 256;
    for (int k = 0; k < 256; k++) acc += emb[k] * w1[k];
    const float* w2 = f2W + (size_t)t * 512;
    for (int a = 0; a < 512; a++) acc += ag[a] * w2[a];
    outNF[(size_t)b * 256 + t] = acc;
}

extern "C" void kernel_launch(void* const* d_in, const int* in_sizes, int n_in,
                              void* d_out, int out_size, void* d_ws, size_t ws_size,
                              hipStream_t stream)
{
    (void)in_sizes; (void)n_in; (void)out_size;
    const float* in_nodes = (const float*)d_in[0];
    const float* in_ef    = (const float*)d_in[1];
    const int*   e_src    = (const int*)d_in[2];
    const int*   e_dst    = (const int*)d_in[3];
    const int*   owner    = (const int*)d_in[4];
    const void*  running  = d_in[5];
    const int*   reft     = (const int*)d_in[6];
    const float* dec_tW = (const float*)d_in[7];
    const float* dec_tb = (const float*)d_in[8];
    const float* dec_gW = (const float*)d_in[9];
    const float* dec_gb = (const float*)d_in[10];
    const float* init_tW = (const float*)d_in[11];
    const float* init_tb = (const float*)d_in[12];
    const float* init_gW = (const float*)d_in[13];
    const float* init_gb = (const float*)d_in[14];
    const float* ntdW = (const float*)d_in[15];
    const float* ntdb = (const float*)d_in[16];
    const float* nte  = (const float*)d_in[17];
    const float* f1W  = (const float*)d_in[18];
    const float* f1b  = (const float*)d_in[19];
    const float* f2W  = (const float*)d_in[20];
    const float* mnW  = (const float*)d_in[21];
    const float* mfW  = (const float*)d_in[22];
    const float* ml2W = (const float*)d_in[23];
    const float* ml2b = (const float*)d_in[24];
    const float* Wih  = (const float*)d_in[25];
    const float* Whh  = (const float*)d_in[26];
    const float* bih  = (const float*)d_in[27];
    const float* bhh  = (const float*)d_in[28];

    float* outL    = (float*)d_out;                        // [512,65] f32
    float* outNF   = outL + BG * (TD + 1);                 // [512,256] f32
    float* outLoss = outNF + BG * SD;                      // [1] f32

    size_t off = 0;
    auto take = [&](size_t bytes) -> void* {
        void* p = (char*)d_ws + off;
        off += (bytes + 255) & ~(size_t)255;
        return p;
    };
    short* nodes_bf  = (short*)take((size_t)NN * SD * 2);      // 33 MB bf16 state
    short* ef_bf     = (short*)take((size_t)EE * SD * 2);      // 67 MB bf16 edge feats
    short* bufC      = (short*)take((size_t)NN * 512 * 2);     // nf
    short* bufD      = (short*)take((size_t)EE * 512 * 2);     // T, later gi[N,768]
    short* bufM      = (short*)take((size_t)EE * 512 * 2);     // msgs, later gh / gp(f32)
    short* bufI      = (short*)take((size_t)NN * 512 * 2);     // inputs bf16
    float* aggD      = (float*)take((size_t)BG * AD * 4);
    float* aggI      = (float*)take((size_t)BG * AD * 4);
    float* logitsF   = (float*)take((size_t)BG * (TD + 1) * 4);
    // bf16 weight copies
    short* mnWb  = (short*)take((size_t)PP * 512 * 256 * 2);
    short* mfWb  = (short*)take((size_t)PP * 512 * 256 * 2);
    short* ml2Wb = (short*)take((size_t)PP * 512 * 512 * 2);
    short* WihB  = (short*)take((size_t)PP * 768 * 512 * 2);
    short* WhhB  = (short*)take((size_t)PP * 768 * 256 * 2);
    short* W2dec = (short*)take((size_t)1024 * 256 * 2);       // interleaved dt/dg
    short* W2ini = (short*)take((size_t)1024 * 256 * 2);       // interleaved it/ig
    // CSR buffers
    int* deg_e = (int*)take((size_t)NN * 4);
    int* offs_e = (int*)take((size_t)(NN + 1) * 4);
    int* cur_e = (int*)take((size_t)NN * 4);
    int* elist = (int*)take((size_t)2 * EE * 4);
    int* degB = (int*)take((size_t)BG * 4);
    int* offsB = (int*)take((size_t)(BG + 1) * 4);
    int* curB = (int*)take((size_t)BG * 4);
    int* nlist = (int*)take((size_t)NN * 4);
    if (off > ws_size) return;

    short* gi = bufD;            // [N,768] bf16 (T dead by then)
    short* gh = bufM;            // [N,768] bf16 (msgs dead by then)
    float* gp = (float*)bufM;    // [N,512] f32 (gh dead by then) — 134 MB fits exactly

    // activation pre-casts (enables global_load_lds path everywhere)
    k_castw<<<NN * SD / 1024, 256, 0, stream>>>(in_nodes, nodes_bf);
    k_castw<<<EE * SD / 1024, 256, 0, stream>>>(in_ef, ef_bf);
    // weight pre-casts
    k_castw<<<PP * 512 * 256 / 1024, 256, 0, stream>>>(mnW, mnWb);
    k_castw<<<PP * 512 * 256 / 1024, 256, 0, stream>>>(mfW, mfWb);
    k_castw<<<PP * 512 * 512 / 1024, 256, 0, stream>>>(ml2W, ml2Wb);
    k_castw<<<PP * 768 * 512 / 1024, 256, 0, stream>>>(Wih, WihB);
    k_castw<<<PP * 768 * 256 / 1024, 256, 0, stream>>>(Whh, WhhB);
    k_cast_pair<<<1024 * 256 / 1024, 256, 0, stream>>>(dec_tW, dec_gW, W2dec);
    k_cast_pair<<<1024 * 256 / 1024, 256, 0, stream>>>(init_tW, init_gW, W2ini);

    // CSR builds (once per launch)
    hipMemsetAsync(deg_e, 0, (size_t)NN * 4, stream);
    hipMemsetAsync(cur_e, 0, (size_t)NN * 4, stream);
    hipMemsetAsync(degB, 0, (size_t)BG * 4, stream);
    hipMemsetAsync(curB, 0, (size_t)BG * 4, stream);
    k_count2<<<(EE + 255) / 256, 256, 0, stream>>>(e_src, e_dst, deg_e, EE);
    k_scan<<<1, 256, 0, stream>>>(deg_e, offs_e, NN);
    k_fill2<<<(EE + 255) / 256, 256, 0, stream>>>(e_src, e_dst, offs_e, cur_e, elist, EE);
    k_count1<<<(NN + 255) / 256, 256, 0, stream>>>(owner, degB, NN);
    k_scan<<<1, 256, 0, stream>>>(degB, offsB, BG);
    k_fill1<<<(NN + 255) / 256, 256, 0, stream>>>(owner, offsB, curB, nlist, NN);

    for (int p = 0; p < PP; p++) {
        // nf = nodes @ mn_W.T            [N,512] bf16
        gemm_bt<0><<<NN / 128 * 4, 256, 0, stream>>>(
            nodes_bf, mnWb + (size_t)p * 512 * 256, nullptr, bufC,
            nullptr, nullptr, nullptr, nullptr, nullptr, 256, 512, 4);
        // T = tanh(nf[src]+nf[dst] + ef@mf_W.T)   [E,512] bf16 (fused epilogue)
        gemm_bt<2><<<EE / 128 * 4, 256, 0, stream>>>(
            ef_bf, mfWb + (size_t)p * 512 * 256, nullptr, bufD,
            nullptr, nullptr, bufC, e_src, e_dst, 256, 512, 4);
        // msgs = T @ ml2.T + ml2_b       [E,512] bf16
        gemm_bt<0><<<EE / 128 * 4, 256, 0, stream>>>(
            bufD, ml2Wb + (size_t)p * 512 * 512, ml2b + (size_t)p * 512,
            bufM, nullptr, nullptr, nullptr, nullptr, nullptr, 512, 512, 4);
        // inputs[n] = sum of msgs over incident edges (CSR gather)
        k_edge_gather<<<NN / 4, 256, 0, stream>>>(bufM, offs_e, elist, bufI);
        // gi = inputs @ Wih.T + bih      [N,768] bf16 (into bufD; T dead)
        gemm_bt<0><<<NN / 128 * 6, 256, 0, stream>>>(
            bufI, WihB + (size_t)p * 768 * 512, bih + (size_t)p * 768, gi,
            nullptr, nullptr, nullptr, nullptr, nullptr, 512, 768, 6);
        // gh = nodes @ Whh.T + bhh       [N,768] bf16 (into bufM; msgs dead)
        gemm_bt<0><<<NN / 128 * 6, 256, 0, stream>>>(
            nodes_bf, WhhB + (size_t)p * 768 * 256, bhh + (size_t)p * 768, gh,
            nullptr, nullptr, nullptr, nullptr, nullptr, 256, 768, 6);
        // GRU combine -> nodes_bf (in place, bf16 state)
        k_gru<<<NN / 4, 256, 0, stream>>>(gi, gh, nodes_bf, owner, running);
    }

    // decision aggregator: single fused GEMM (interleaved data/gate W, NC=1024)
    gemm_bt<4><<<NN / 128 * 8, 256, 0, stream>>>(
        nodes_bf, W2dec, dec_tb, nullptr, gp, dec_gb,
        nullptr, nullptr, nullptr, 256, 1024, 8);
    k_owner_reduce<<<BG, 256, 0, stream>>>(gp, offsB, nlist, aggD);
    // init aggregator
    gemm_bt<4><<<NN / 128 * 8, 256, 0, stream>>>(
        nodes_bf, W2ini, init_tb, nullptr, gp, init_gb,
        nullptr, nullptr, nullptr, 256, 1024, 8);
    k_owner_reduce<<<BG, 256, 0, stream>>>(gp, offsB, nlist, aggI);

    k_logits<<<BG, 128, 0, stream>>>(aggD, ntdW, ntdb, logitsF, outL);
    k_loss<<<1, 512, 0, stream>>>(logitsF, reft, running, outLoss);
    k_newfeat<<<BG, 256, 0, stream>>>(aggI, nte, reft, f1W, f1b, f2W, outNF);
}